// Round 14
// baseline (207.901 us; speedup 1.0000x reference)
//
#include <hip/hip_runtime.h>

#define N_NODES 50000
#define N_EDGES 600000
#define DIM 128
#define NCLS 10
#define NPART 8                  // XCD partitions (blockIdx & 7)
#define ELLW_P 16                // per-partition max degree (Poisson(1.5); P(>16)~1e-13)
#define EPSF 1e-15f
#define MAXNORM 0.99999f         // 1 - 1e-5
#define NTILE ((N_NODES + 63) / 64)   // 782
#define FILLB 2344               // ceil(600000/256), 1 edge/thread
#define XFB 512                  // persistent transform blocks

typedef __attribute__((ext_vector_type(8))) short bf16x8;
typedef __attribute__((ext_vector_type(4))) float f32x4;

__device__ inline float waveSum(float v) {
#pragma unroll
  for (int o = 1; o < 64; o <<= 1) v += __shfl_xor(v, o, 64);
  return v;
}

__device__ inline unsigned short f2bf(float f) {
  union { float f; unsigned u; } c; c.f = f;
  return (unsigned short)((c.u + 0x7FFFu + ((c.u >> 16) & 1u)) >> 16);
}
__device__ inline float bf_lo(unsigned u) {
  union { unsigned u; float f; } c; c.u = u << 16; return c.f;
}
__device__ inline float bf_hi(unsigned u) {
  union { unsigned u; float f; } c; c.u = u & 0xFFFF0000u; return c.f;
}

// ---------------- init: zero partitioned cursors + convert W1/W2 to bf16 ---------
__global__ __launch_bounds__(256) void init_kernel(
    int* __restrict__ cur, const float* __restrict__ W1, const float* __restrict__ W2,
    unsigned short* __restrict__ W1b, unsigned short* __restrict__ W2b)
{
  int i = blockIdx.x * 256 + threadIdx.x;
  if (i < NPART * N_NODES) cur[i] = 0;
  if (i < DIM * DIM) {
    W1b[i] = f2bf(W1[i]);
    W2b[i] = f2bf(W2[i]);
  }
}

// ---------------- fused: XCD-partitioned ELL fill + layer-1 transform ------------
// Fill blocks (bid < FILLB): 1 edge/thread; partition = bid & 7 keeps every
// cursor/ELL cache line owned by one XCD's L2 (no cross-XCD ping-pong).
// Transform blocks: logmap0 -> W1*t+b1 (MFMA, W in VGPRs) -> expmap0 -> bf16 y.
__global__ __launch_bounds__(256, 2) void fill_transform(
    const int* __restrict__ src, const int* __restrict__ dst,
    int* __restrict__ cur, int* __restrict__ ell,
    const float* __restrict__ x, const unsigned short* __restrict__ Wb,
    const float* __restrict__ b, unsigned short* __restrict__ y)
{
  __shared__ __align__(16) unsigned short At[64 * DIM];

  if (blockIdx.x < FILLB) {
    const int e = blockIdx.x * 256 + threadIdx.x;
    if (e < N_EDGES) {
      const int part = blockIdx.x & (NPART - 1);
      int d = dst[e];
      int s = src[e];
      int p = atomicAdd(&cur[part * N_NODES + d], 1);
      if (p < ELLW_P) ell[((size_t)part * N_NODES + d) * ELLW_P + p] = s;
    }
    return;
  }

  // ---------------- transform path (layer 1: f32 manifold in) ----------------
  const int tid = threadIdx.x;
  const int w = tid >> 6;
  const int l = tid & 63;
  const int lr = l & 15;
  const int lg = l >> 4;

  bf16x8 bf[8][4];
#pragma unroll
  for (int n = 0; n < 8; ++n)
#pragma unroll
    for (int kc = 0; kc < 4; ++kc)
      bf[n][kc] = *(const bf16x8*)(Wb + (n * 16 + lr) * DIM + kc * 32 + lg * 8);

  float bias[8];
#pragma unroll
  for (int n = 0; n < 8; ++n) bias[n] = b[n * 16 + lr];

  const int row = w * 16 + lr;

  for (int tile = blockIdx.x - FILLB; tile < NTILE; tile += XFB) {
    const int base = tile * 64;
    const int node = base + row;
    __syncthreads();

    float v[32];
    if (node < N_NODES) {
      const float4* xr = (const float4*)(x + (size_t)node * DIM + lg * 32);
#pragma unroll
      for (int q = 0; q < 8; ++q) {
        float4 f = xr[q];
        v[q * 4 + 0] = f.x; v[q * 4 + 1] = f.y; v[q * 4 + 2] = f.z; v[q * 4 + 3] = f.w;
      }
    } else {
#pragma unroll
      for (int q = 0; q < 32; ++q) v[q] = 0.f;
    }
    float sq = 0.f;
#pragma unroll
    for (int q = 0; q < 32; ++q) sq += v[q] * v[q];
    sq += __shfl_xor(sq, 16, 64);
    sq += __shfl_xor(sq, 32, 64);
    float n1 = sqrtf(sq);
    float nc = fmaxf(n1, EPSF);
    float nm = fminf(nc, MAXNORM);
    float scale = 0.5f * logf((1.f + nm) / (1.f - nm)) / nc;
#pragma unroll
    for (int s = 0; s < 4; ++s) {
      unsigned short tmp[8];
#pragma unroll
      for (int e = 0; e < 8; ++e) tmp[e] = f2bf(v[s * 8 + e] * scale);
      int byte = row * 256 + lg * 64 + s * 16;
      byte ^= (row & 7) << 4;
      *(bf16x8*)((char*)At + byte) = *(const bf16x8*)tmp;
    }
    __syncthreads();

    f32x4 acc[8];
#pragma unroll
    for (int n = 0; n < 8; ++n) {
      acc[n][0] = bias[n]; acc[n][1] = bias[n]; acc[n][2] = bias[n]; acc[n][3] = bias[n];
    }
#pragma unroll
    for (int kc = 0; kc < 4; ++kc) {
      int byte = row * 256 + kc * 64 + lg * 16;
      byte ^= (row & 7) << 4;
      bf16x8 af = *(const bf16x8*)((const char*)At + byte);
#pragma unroll
      for (int n = 0; n < 8; ++n)
        acc[n] = __builtin_amdgcn_mfma_f32_16x16x32_bf16(af, bf[n][kc], acc[n], 0, 0, 0);
    }

    float rs[4];
#pragma unroll
    for (int j = 0; j < 4; ++j) {
      float s2 = 0.f;
#pragma unroll
      for (int n = 0; n < 8; ++n) s2 += acc[n][j] * acc[n][j];
      s2 += __shfl_xor(s2, 1, 64);
      s2 += __shfl_xor(s2, 2, 64);
      s2 += __shfl_xor(s2, 4, 64);
      s2 += __shfl_xor(s2, 8, 64);
      float n2 = sqrtf(s2);
      float n2c = fmaxf(n2, EPSF);
      rs[j] = tanhf(n2c) / n2c;
    }
#pragma unroll
    for (int j = 0; j < 4; ++j) {
      int nrow = base + w * 16 + lg * 4 + j;
      if (nrow < N_NODES) {
        unsigned short* yr = y + (size_t)nrow * DIM + lr;
#pragma unroll
        for (int n = 0; n < 8; ++n) yr[n * 16] = f2bf(acc[n][j] * rs[j]);
      }
    }
  }
}

// ---------------- gather (8 partitions) + relu + logmap0 -> bf16 tangent ---------
__global__ __launch_bounds__(256) void gatherT_kernel(
    const unsigned short* __restrict__ y, const int* __restrict__ cur,
    const int* __restrict__ ell, unsigned short* __restrict__ tout)
{
  const int node = blockIdx.x * 4 + (threadIdx.x >> 6);
  if (node >= N_NODES) return;
  const int lane = threadIdx.x & 63;
  float2 a0 = {0.f, 0.f}, a1 = {0.f, 0.f};
#pragma unroll
  for (int part = 0; part < NPART; ++part) {
    int cnt = cur[part * N_NODES + node];
    cnt = min(cnt, ELLW_P);
    const int* lst = ell + ((size_t)part * N_NODES + node) * ELLW_P;
    int j = 0;
    for (; j + 1 < cnt; j += 2) {
      int s0 = lst[j], s1 = lst[j + 1];
      unsigned u0 = ((const unsigned*)(y + (size_t)s0 * DIM))[lane];
      unsigned u1 = ((const unsigned*)(y + (size_t)s1 * DIM))[lane];
      a0.x += bf_lo(u0); a0.y += bf_hi(u0);
      a1.x += bf_lo(u1); a1.y += bf_hi(u1);
    }
    if (j < cnt) {
      unsigned u0 = ((const unsigned*)(y + (size_t)lst[j] * DIM))[lane];
      a0.x += bf_lo(u0); a0.y += bf_hi(u0);
    }
  }
  float2 r;
  r.x = fmaxf(a0.x + a1.x, 0.f);  // relu
  r.y = fmaxf(a0.y + a1.y, 0.f);

  // logmap0 across the wave-held 128-dim row
  float s = waveSum(r.x * r.x + r.y * r.y);
  float n = sqrtf(s);
  float nc = fmaxf(n, EPSF);
  float nm = fminf(nc, MAXNORM);
  float scale = 0.5f * logf((1.0f + nm) / (1.0f - nm)) / nc;
  unsigned u = (unsigned)f2bf(r.x * scale) | ((unsigned)f2bf(r.y * scale) << 16);
  ((unsigned*)(tout + (size_t)node * DIM))[lane] = u;
}

// ---------------- layer-2 transform: bf16 tangent in -> (W t + b) -> expmap0 ------
__global__ __launch_bounds__(256, 2) void transform2_mfma(
    const unsigned short* __restrict__ t, const unsigned short* __restrict__ Wb,
    const float* __restrict__ b, unsigned short* __restrict__ y)
{
  const int tid = threadIdx.x;
  const int w = tid >> 6;
  const int l = tid & 63;
  const int lr = l & 15;
  const int lg = l >> 4;

  __shared__ __align__(16) unsigned short At[64 * DIM];

  bf16x8 bf[8][4];
#pragma unroll
  for (int n = 0; n < 8; ++n)
#pragma unroll
    for (int kc = 0; kc < 4; ++kc)
      bf[n][kc] = *(const bf16x8*)(Wb + (n * 16 + lr) * DIM + kc * 32 + lg * 8);

  float bias[8];
#pragma unroll
  for (int n = 0; n < 8; ++n) bias[n] = b[n * 16 + lr];

  const int row = w * 16 + lr;

  for (int tile = blockIdx.x; tile < NTILE; tile += gridDim.x) {
    const int base = tile * 64;
    const int node = base + row;
    __syncthreads();

#pragma unroll
    for (int s = 0; s < 4; ++s) {
      bf16x8 frag;
      if (node < N_NODES)
        frag = *(const bf16x8*)(t + (size_t)node * DIM + lg * 32 + s * 8);
      else
        frag = bf16x8{0, 0, 0, 0, 0, 0, 0, 0};
      int byte = row * 256 + lg * 64 + s * 16;
      byte ^= (row & 7) << 4;
      *(bf16x8*)((char*)At + byte) = frag;
    }
    __syncthreads();

    f32x4 acc[8];
#pragma unroll
    for (int n = 0; n < 8; ++n) {
      acc[n][0] = bias[n]; acc[n][1] = bias[n]; acc[n][2] = bias[n]; acc[n][3] = bias[n];
    }
#pragma unroll
    for (int kc = 0; kc < 4; ++kc) {
      int byte = row * 256 + kc * 64 + lg * 16;
      byte ^= (row & 7) << 4;
      bf16x8 af = *(const bf16x8*)((const char*)At + byte);
#pragma unroll
      for (int n = 0; n < 8; ++n)
        acc[n] = __builtin_amdgcn_mfma_f32_16x16x32_bf16(af, bf[n][kc], acc[n], 0, 0, 0);
    }

    float rs[4];
#pragma unroll
    for (int j = 0; j < 4; ++j) {
      float s2 = 0.f;
#pragma unroll
      for (int n = 0; n < 8; ++n) s2 += acc[n][j] * acc[n][j];
      s2 += __shfl_xor(s2, 1, 64);
      s2 += __shfl_xor(s2, 2, 64);
      s2 += __shfl_xor(s2, 4, 64);
      s2 += __shfl_xor(s2, 8, 64);
      float n2 = sqrtf(s2);
      float n2c = fmaxf(n2, EPSF);
      rs[j] = tanhf(n2c) / n2c;
    }
#pragma unroll
    for (int j = 0; j < 4; ++j) {
      int nrow = base + w * 16 + lg * 4 + j;
      if (nrow < N_NODES) {
        unsigned short* yr = y + (size_t)nrow * DIM + lr;
#pragma unroll
        for (int n = 0; n < 8; ++n) yr[n * 16] = f2bf(acc[n][j] * rs[j]);
      }
    }
  }
}

// ---------------- classifier head: out = t2 @ Wc^T + bc via MFMA ----------------
__global__ __launch_bounds__(256) void head_mfma(
    const unsigned short* __restrict__ t2, const float* __restrict__ Wc,
    const float* __restrict__ bc, float* __restrict__ out)
{
  const int base = blockIdx.x * 64;
  const int w = threadIdx.x >> 6;
  const int l = threadIdx.x & 63;
  const int lr = l & 15;
  const int lg = l >> 4;

  bf16x8 bw[4];
#pragma unroll
  for (int kc = 0; kc < 4; ++kc) {
    unsigned short tmp[8];
    if (lr < NCLS) {
      const float* wr = Wc + (size_t)lr * DIM + kc * 32 + lg * 8;
#pragma unroll
      for (int e = 0; e < 8; ++e) tmp[e] = f2bf(wr[e]);
    } else {
#pragma unroll
      for (int e = 0; e < 8; ++e) tmp[e] = 0;
    }
    bw[kc] = *(const bf16x8*)tmp;
  }
  const float bias = (lr < NCLS) ? bc[lr] : 0.f;

  const int arow = base + w * 16 + lr;
  f32x4 acc;
  acc[0] = bias; acc[1] = bias; acc[2] = bias; acc[3] = bias;
#pragma unroll
  for (int kc = 0; kc < 4; ++kc) {
    bf16x8 af;
    if (arow < N_NODES)
      af = *(const bf16x8*)(t2 + (size_t)arow * DIM + kc * 32 + lg * 8);
    else
      af = bf16x8{0, 0, 0, 0, 0, 0, 0, 0};
    acc = __builtin_amdgcn_mfma_f32_16x16x32_bf16(af, bw[kc], acc, 0, 0, 0);
  }

  if (lr < NCLS) {
#pragma unroll
    for (int j = 0; j < 4; ++j) {
      int nrow = base + w * 16 + lg * 4 + j;
      if (nrow < N_NODES) out[(size_t)nrow * NCLS + lr] = acc[j];
    }
  }
}

extern "C" void kernel_launch(void* const* d_in, const int* in_sizes, int n_in,
                              void* d_out, int out_size, void* d_ws, size_t ws_size,
                              hipStream_t stream)
{
  const int* edge = (const int*)d_in[0];
  const int* src = edge;            // edge_index[0]
  const int* dst = edge + N_EDGES;  // edge_index[1]
  const float* x  = (const float*)d_in[1];
  const float* W1 = (const float*)d_in[2];
  const float* b1 = (const float*)d_in[3];
  const float* W2 = (const float*)d_in[4];
  const float* b2 = (const float*)d_in[5];
  const float* Wc = (const float*)d_in[6];
  const float* bc = (const float*)d_in[7];
  float* out = (float*)d_out;

  unsigned short* ybuf = (unsigned short*)d_ws;          // bf16 y [N, D]
  unsigned short* tbuf = ybuf + (size_t)N_NODES * DIM;   // bf16 tangent [N, D]
  unsigned short* W1b = tbuf + (size_t)N_NODES * DIM;
  unsigned short* W2b = W1b + DIM * DIM;
  int* cur = (int*)(W2b + DIM * DIM);                    // NPART * N_NODES
  int* ell = cur + NPART * N_NODES;                      // NPART * N_NODES * ELLW_P

  // --- init (zero partitioned cursors) + W->bf16 ---
  init_kernel<<<(NPART * N_NODES + 255) / 256, 256, 0, stream>>>(cur, W1, W2, W1b, W2b);

  // --- XCD-partitioned ELL fill || layer-1 transform ---
  fill_transform<<<FILLB + XFB, 256, 0, stream>>>(src, dst, cur, ell, x, W1b, b1, ybuf);

  // --- gather + relu + logmap -> t (bf16) ---
  gatherT_kernel<<<(N_NODES + 3) / 4, 256, 0, stream>>>(ybuf, cur, ell, tbuf);

  // --- Layer 2: t (bf16 tangent) -> y2 (bf16) ---
  transform2_mfma<<<512, 256, 0, stream>>>(tbuf, W2b, b2, ybuf);

  // --- gather + relu + logmap -> t2 (bf16) ---
  gatherT_kernel<<<(N_NODES + 3) / 4, 256, 0, stream>>>(ybuf, cur, ell, tbuf);

  // --- classifier head ---
  head_mfma<<<NTILE, 256, 0, stream>>>(tbuf, Wc, bc, out);
}

// Round 15
// 161.339 us; speedup vs baseline: 1.2886x; 1.2886x over previous
//
#include <hip/hip_runtime.h>

#define N_NODES 50000
#define N_EDGES 600000
#define DIM 128
#define NCLS 10
#define ELLW 64                 // max degree (mean 12)
#define CURSTRIDE 16            // one cursor per 64B line
#define EPSF 1e-15f
#define MAXNORM 0.99999f        // 1 - 1e-5
#define NTILE ((N_NODES + 63) / 64)   // 782
#define FILLB 586               // ceil(600000/(256*4))
#define XFB 512                 // persistent transform blocks
#define HALFN 25000
#define GSB (8 * 1563)          // gather_slice blocks: 8 parts x ceil(25000/16)

typedef __attribute__((ext_vector_type(8))) short bf16x8;
typedef __attribute__((ext_vector_type(4))) float f32x4;

__device__ inline unsigned short f2bf(float f) {
  union { float f; unsigned u; } c; c.f = f;
  return (unsigned short)((c.u + 0x7FFFu + ((c.u >> 16) & 1u)) >> 16);
}
__device__ inline float bf2f(unsigned short s) {
  union { unsigned u; float f; } c; c.u = (unsigned)s << 16; return c.f;
}
__device__ inline float bf_lo(unsigned u) {
  union { unsigned u; float f; } c; c.u = u << 16; return c.f;
}
__device__ inline float bf_hi(unsigned u) {
  union { unsigned u; float f; } c; c.u = u & 0xFFFF0000u; return c.f;
}

// ---------------- init: zero cursors + convert W1/W2 to bf16 ----------------
__global__ __launch_bounds__(256) void init_kernel(
    int* __restrict__ cursor, const float* __restrict__ W1, const float* __restrict__ W2,
    unsigned short* __restrict__ W1b, unsigned short* __restrict__ W2b)
{
  int i = blockIdx.x * 256 + threadIdx.x;
  if (i < N_NODES) cursor[i * CURSTRIDE] = 0;
  if (i < DIM * DIM) {
    W1b[i] = f2bf(W1[i]);
    W2b[i] = f2bf(W2[i]);
  }
}

// ---------------- fused: ELL fill + layer-1 transform (R10 structure) ------------
__global__ __launch_bounds__(256, 2) void fill_transform(
    const int* __restrict__ src, const int* __restrict__ dst,
    int* __restrict__ cursor, int* __restrict__ ell,
    const float* __restrict__ x, const unsigned short* __restrict__ Wb,
    const float* __restrict__ b, unsigned short* __restrict__ y)
{
  __shared__ __align__(16) unsigned short At[64 * DIM];

  if (blockIdx.x < FILLB) {
    const int nthr = FILLB * 256;
    const int e = blockIdx.x * 256 + threadIdx.x;
    const int e0 = e, e1 = e + nthr, e2 = e + 2 * nthr, e3 = e + 3 * nthr;
    int d0, d1, d2, d3, s0, s1, s2, s3;
    if (e0 < N_EDGES) { d0 = dst[e0]; s0 = src[e0]; }
    if (e1 < N_EDGES) { d1 = dst[e1]; s1 = src[e1]; }
    if (e2 < N_EDGES) { d2 = dst[e2]; s2 = src[e2]; }
    if (e3 < N_EDGES) { d3 = dst[e3]; s3 = src[e3]; }
    int p0, p1, p2, p3;
    if (e0 < N_EDGES) p0 = atomicAdd(&cursor[d0 * CURSTRIDE], 1);
    if (e1 < N_EDGES) p1 = atomicAdd(&cursor[d1 * CURSTRIDE], 1);
    if (e2 < N_EDGES) p2 = atomicAdd(&cursor[d2 * CURSTRIDE], 1);
    if (e3 < N_EDGES) p3 = atomicAdd(&cursor[d3 * CURSTRIDE], 1);
    if (e0 < N_EDGES) ell[d0 * ELLW + p0] = s0;
    if (e1 < N_EDGES) ell[d1 * ELLW + p1] = s1;
    if (e2 < N_EDGES) ell[d2 * ELLW + p2] = s2;
    if (e3 < N_EDGES) ell[d3 * ELLW + p3] = s3;
    return;
  }

  // ---------------- transform path (layer 1: f32 manifold in) ----------------
  const int tid = threadIdx.x;
  const int w = tid >> 6;
  const int l = tid & 63;
  const int lr = l & 15;
  const int lg = l >> 4;

  bf16x8 bf[8][4];
#pragma unroll
  for (int n = 0; n < 8; ++n)
#pragma unroll
    for (int kc = 0; kc < 4; ++kc)
      bf[n][kc] = *(const bf16x8*)(Wb + (n * 16 + lr) * DIM + kc * 32 + lg * 8);

  float bias[8];
#pragma unroll
  for (int n = 0; n < 8; ++n) bias[n] = b[n * 16 + lr];

  const int row = w * 16 + lr;

  for (int tile = blockIdx.x - FILLB; tile < NTILE; tile += XFB) {
    const int base = tile * 64;
    const int node = base + row;
    __syncthreads();

    float v[32];
    if (node < N_NODES) {
      const float4* xr = (const float4*)(x + (size_t)node * DIM + lg * 32);
#pragma unroll
      for (int q = 0; q < 8; ++q) {
        float4 f = xr[q];
        v[q * 4 + 0] = f.x; v[q * 4 + 1] = f.y; v[q * 4 + 2] = f.z; v[q * 4 + 3] = f.w;
      }
    } else {
#pragma unroll
      for (int q = 0; q < 32; ++q) v[q] = 0.f;
    }
    float sq = 0.f;
#pragma unroll
    for (int q = 0; q < 32; ++q) sq += v[q] * v[q];
    sq += __shfl_xor(sq, 16, 64);
    sq += __shfl_xor(sq, 32, 64);
    float n1 = sqrtf(sq);
    float nc = fmaxf(n1, EPSF);
    float nm = fminf(nc, MAXNORM);
    float scale = 0.5f * logf((1.f + nm) / (1.f - nm)) / nc;
#pragma unroll
    for (int s = 0; s < 4; ++s) {
      unsigned short tmp[8];
#pragma unroll
      for (int e = 0; e < 8; ++e) tmp[e] = f2bf(v[s * 8 + e] * scale);
      int byte = row * 256 + lg * 64 + s * 16;
      byte ^= (row & 7) << 4;
      *(bf16x8*)((char*)At + byte) = *(const bf16x8*)tmp;
    }
    __syncthreads();

    f32x4 acc[8];
#pragma unroll
    for (int n = 0; n < 8; ++n) {
      acc[n][0] = bias[n]; acc[n][1] = bias[n]; acc[n][2] = bias[n]; acc[n][3] = bias[n];
    }
#pragma unroll
    for (int kc = 0; kc < 4; ++kc) {
      int byte = row * 256 + kc * 64 + lg * 16;
      byte ^= (row & 7) << 4;
      bf16x8 af = *(const bf16x8*)((const char*)At + byte);
#pragma unroll
      for (int n = 0; n < 8; ++n)
        acc[n] = __builtin_amdgcn_mfma_f32_16x16x32_bf16(af, bf[n][kc], acc[n], 0, 0, 0);
    }

    float rs[4];
#pragma unroll
    for (int j = 0; j < 4; ++j) {
      float s2 = 0.f;
#pragma unroll
      for (int n = 0; n < 8; ++n) s2 += acc[n][j] * acc[n][j];
      s2 += __shfl_xor(s2, 1, 64);
      s2 += __shfl_xor(s2, 2, 64);
      s2 += __shfl_xor(s2, 4, 64);
      s2 += __shfl_xor(s2, 8, 64);
      float n2 = sqrtf(s2);
      float n2c = fmaxf(n2, EPSF);
      rs[j] = tanhf(n2c) / n2c;
    }
#pragma unroll
    for (int j = 0; j < 4; ++j) {
      int nrow = base + w * 16 + lg * 4 + j;
      if (nrow < N_NODES) {
        unsigned short* yr = y + (size_t)nrow * DIM + lr;
#pragma unroll
        for (int n = 0; n < 8; ++n) yr[n * 16] = f2bf(acc[n][j] * rs[j]);
      }
    }
  }
}

// ---------------- gather_slice: raw segment-sum, one 64B line per XCD ------------
// blockIdx&7 -> (line, node-half): each XCD touches only ybuf[:, line*32..+32)
// (3.2MB, L2-resident). 16-lane group = one node's slice. Output: raw bf16 h.
__global__ __launch_bounds__(256) void gather_slice(
    const unsigned short* __restrict__ y, const int* __restrict__ cursor,
    const int* __restrict__ ell, unsigned short* __restrict__ h)
{
  const int part = blockIdx.x & 7;
  const int line = part >> 1;          // 0..3: 64B line within the row
  const int half = part & 1;           // node half
  const int local = (blockIdx.x >> 3) * 16 + (threadIdx.x >> 4);
  if (local >= HALFN) return;
  const int node = half * HALFN + local;
  const int lane16 = threadIdx.x & 15;
  const int cnt = cursor[node * CURSTRIDE];
  const int* lst = ell + (size_t)node * ELLW;
  const unsigned short* yb = y + line * 32;
  float ax0 = 0.f, ay0 = 0.f, ax1 = 0.f, ay1 = 0.f;
  float ax2 = 0.f, ay2 = 0.f, ax3 = 0.f, ay3 = 0.f;
  int j = 0;
  for (; j + 3 < cnt; j += 4) {
    unsigned u0 = ((const unsigned*)(yb + (size_t)lst[j    ] * DIM))[lane16];
    unsigned u1 = ((const unsigned*)(yb + (size_t)lst[j + 1] * DIM))[lane16];
    unsigned u2 = ((const unsigned*)(yb + (size_t)lst[j + 2] * DIM))[lane16];
    unsigned u3 = ((const unsigned*)(yb + (size_t)lst[j + 3] * DIM))[lane16];
    ax0 += bf_lo(u0); ay0 += bf_hi(u0);
    ax1 += bf_lo(u1); ay1 += bf_hi(u1);
    ax2 += bf_lo(u2); ay2 += bf_hi(u2);
    ax3 += bf_lo(u3); ay3 += bf_hi(u3);
  }
  for (; j < cnt; ++j) {
    unsigned u0 = ((const unsigned*)(yb + (size_t)lst[j] * DIM))[lane16];
    ax0 += bf_lo(u0); ay0 += bf_hi(u0);
  }
  float rx = (ax0 + ax1) + (ax2 + ax3);
  float ry = (ay0 + ay1) + (ay2 + ay3);
  unsigned u = (unsigned)f2bf(rx) | ((unsigned)f2bf(ry) << 16);
  ((unsigned*)(h + (size_t)node * DIM + line * 32))[lane16] = u;
}

// ---------------- layer-2 transform: bf16 raw h -> relu -> logmap -> MFMA -> expmap0
__global__ __launch_bounds__(256, 2) void transform2_mfma(
    const unsigned short* __restrict__ h, const unsigned short* __restrict__ Wb,
    const float* __restrict__ b, unsigned short* __restrict__ y)
{
  const int tid = threadIdx.x;
  const int w = tid >> 6;
  const int l = tid & 63;
  const int lr = l & 15;
  const int lg = l >> 4;

  __shared__ __align__(16) unsigned short At[64 * DIM];

  bf16x8 bf[8][4];
#pragma unroll
  for (int n = 0; n < 8; ++n)
#pragma unroll
    for (int kc = 0; kc < 4; ++kc)
      bf[n][kc] = *(const bf16x8*)(Wb + (n * 16 + lr) * DIM + kc * 32 + lg * 8);

  float bias[8];
#pragma unroll
  for (int n = 0; n < 8; ++n) bias[n] = b[n * 16 + lr];

  const int row = w * 16 + lr;

  for (int tile = blockIdx.x; tile < NTILE; tile += gridDim.x) {
    const int base = tile * 64;
    const int node = base + row;
    __syncthreads();

    // relu + logmap0 from bf16 h (lane holds dims lg*32..+31 of its row)
    float v[32];
    if (node < N_NODES) {
      const unsigned short* hr = h + (size_t)node * DIM + lg * 32;
#pragma unroll
      for (int s = 0; s < 4; ++s) {
        bf16x8 frag = *(const bf16x8*)(hr + s * 8);
#pragma unroll
        for (int e = 0; e < 8; ++e)
          v[s * 8 + e] = fmaxf(bf2f((unsigned short)frag[e]), 0.f);
      }
    } else {
#pragma unroll
      for (int q = 0; q < 32; ++q) v[q] = 0.f;
    }
    float sq = 0.f;
#pragma unroll
    for (int q = 0; q < 32; ++q) sq += v[q] * v[q];
    sq += __shfl_xor(sq, 16, 64);
    sq += __shfl_xor(sq, 32, 64);
    float n1 = sqrtf(sq);
    float nc = fmaxf(n1, EPSF);
    float nm = fminf(nc, MAXNORM);
    float scale = 0.5f * logf((1.f + nm) / (1.f - nm)) / nc;
#pragma unroll
    for (int s = 0; s < 4; ++s) {
      unsigned short tmp[8];
#pragma unroll
      for (int e = 0; e < 8; ++e) tmp[e] = f2bf(v[s * 8 + e] * scale);
      int byte = row * 256 + lg * 64 + s * 16;
      byte ^= (row & 7) << 4;
      *(bf16x8*)((char*)At + byte) = *(const bf16x8*)tmp;
    }
    __syncthreads();

    f32x4 acc[8];
#pragma unroll
    for (int n = 0; n < 8; ++n) {
      acc[n][0] = bias[n]; acc[n][1] = bias[n]; acc[n][2] = bias[n]; acc[n][3] = bias[n];
    }
#pragma unroll
    for (int kc = 0; kc < 4; ++kc) {
      int byte = row * 256 + kc * 64 + lg * 16;
      byte ^= (row & 7) << 4;
      bf16x8 af = *(const bf16x8*)((const char*)At + byte);
#pragma unroll
      for (int n = 0; n < 8; ++n)
        acc[n] = __builtin_amdgcn_mfma_f32_16x16x32_bf16(af, bf[n][kc], acc[n], 0, 0, 0);
    }

    float rs[4];
#pragma unroll
    for (int j = 0; j < 4; ++j) {
      float s2 = 0.f;
#pragma unroll
      for (int n = 0; n < 8; ++n) s2 += acc[n][j] * acc[n][j];
      s2 += __shfl_xor(s2, 1, 64);
      s2 += __shfl_xor(s2, 2, 64);
      s2 += __shfl_xor(s2, 4, 64);
      s2 += __shfl_xor(s2, 8, 64);
      float n2 = sqrtf(s2);
      float n2c = fmaxf(n2, EPSF);
      rs[j] = tanhf(n2c) / n2c;
    }
#pragma unroll
    for (int j = 0; j < 4; ++j) {
      int nrow = base + w * 16 + lg * 4 + j;
      if (nrow < N_NODES) {
        unsigned short* yr = y + (size_t)nrow * DIM + lr;
#pragma unroll
        for (int n = 0; n < 8; ++n) yr[n * 16] = f2bf(acc[n][j] * rs[j]);
      }
    }
  }
}

// ---------------- head: relu -> logmap -> t2 @ Wc^T + bc via MFMA ----------------
__global__ __launch_bounds__(256) void head_mfma(
    const unsigned short* __restrict__ h2, const float* __restrict__ Wc,
    const float* __restrict__ bc, float* __restrict__ out)
{
  const int base = blockIdx.x * 64;
  const int w = threadIdx.x >> 6;
  const int l = threadIdx.x & 63;
  const int lr = l & 15;
  const int lg = l >> 4;

  bf16x8 bw[4];
#pragma unroll
  for (int kc = 0; kc < 4; ++kc) {
    unsigned short tmp[8];
    if (lr < NCLS) {
      const float* wr = Wc + (size_t)lr * DIM + kc * 32 + lg * 8;
#pragma unroll
      for (int e = 0; e < 8; ++e) tmp[e] = f2bf(wr[e]);
    } else {
#pragma unroll
      for (int e = 0; e < 8; ++e) tmp[e] = 0;
    }
    bw[kc] = *(const bf16x8*)tmp;
  }
  const float bias = (lr < NCLS) ? bc[lr] : 0.f;

  const int arow = base + w * 16 + lr;

  // relu + logmap0: lane holds dims [kc*32 + lg*8 .. +8) of row arow
  float va[32];
  if (arow < N_NODES) {
    const unsigned short* hr = h2 + (size_t)arow * DIM;
#pragma unroll
    for (int kc = 0; kc < 4; ++kc) {
      bf16x8 f = *(const bf16x8*)(hr + kc * 32 + lg * 8);
#pragma unroll
      for (int e = 0; e < 8; ++e)
        va[kc * 8 + e] = fmaxf(bf2f((unsigned short)f[e]), 0.f);
    }
  } else {
#pragma unroll
    for (int q = 0; q < 32; ++q) va[q] = 0.f;
  }
  float sq = 0.f;
#pragma unroll
  for (int q = 0; q < 32; ++q) sq += va[q] * va[q];
  sq += __shfl_xor(sq, 16, 64);
  sq += __shfl_xor(sq, 32, 64);
  float n1 = sqrtf(sq);
  float nc = fmaxf(n1, EPSF);
  float nm = fminf(nc, MAXNORM);
  float scale = 0.5f * logf((1.f + nm) / (1.f - nm)) / nc;

  f32x4 acc;
  acc[0] = bias; acc[1] = bias; acc[2] = bias; acc[3] = bias;
#pragma unroll
  for (int kc = 0; kc < 4; ++kc) {
    unsigned short tmp[8];
#pragma unroll
    for (int e = 0; e < 8; ++e) tmp[e] = f2bf(va[kc * 8 + e] * scale);
    bf16x8 af = *(const bf16x8*)tmp;
    acc = __builtin_amdgcn_mfma_f32_16x16x32_bf16(af, bw[kc], acc, 0, 0, 0);
  }

  if (lr < NCLS) {
#pragma unroll
    for (int j = 0; j < 4; ++j) {
      int nrow = base + w * 16 + lg * 4 + j;
      if (nrow < N_NODES) out[(size_t)nrow * NCLS + lr] = acc[j];
    }
  }
}

extern "C" void kernel_launch(void* const* d_in, const int* in_sizes, int n_in,
                              void* d_out, int out_size, void* d_ws, size_t ws_size,
                              hipStream_t stream)
{
  const int* edge = (const int*)d_in[0];
  const int* src = edge;            // edge_index[0]
  const int* dst = edge + N_EDGES;  // edge_index[1]
  const float* x  = (const float*)d_in[1];
  const float* W1 = (const float*)d_in[2];
  const float* b1 = (const float*)d_in[3];
  const float* W2 = (const float*)d_in[4];
  const float* b2 = (const float*)d_in[5];
  const float* Wc = (const float*)d_in[6];
  const float* bc = (const float*)d_in[7];
  float* out = (float*)d_out;

  unsigned short* ybuf = (unsigned short*)d_ws;          // bf16 y [N, D]
  unsigned short* hbuf = ybuf + (size_t)N_NODES * DIM;   // bf16 raw segment-sum [N, D]
  unsigned short* W1b = hbuf + (size_t)N_NODES * DIM;
  unsigned short* W2b = W1b + DIM * DIM;
  int* cursor = (int*)(W2b + DIM * DIM);                 // N_NODES * CURSTRIDE
  int* ell = cursor + (size_t)N_NODES * CURSTRIDE;       // N_NODES * ELLW

  // --- init (zero cursors) + W->bf16 ---
  init_kernel<<<(N_NODES + 255) / 256, 256, 0, stream>>>(cursor, W1, W2, W1b, W2b);

  // --- ELL fill || layer-1 transform -> ybuf ---
  fill_transform<<<FILLB + XFB, 256, 0, stream>>>(src, dst, cursor, ell, x, W1b, b1, ybuf);

  // --- sliced gather (raw sums): ybuf -> hbuf ---
  gather_slice<<<GSB, 256, 0, stream>>>(ybuf, cursor, ell, hbuf);

  // --- layer 2: relu+logmap+MFMA+expmap: hbuf -> ybuf ---
  transform2_mfma<<<512, 256, 0, stream>>>(hbuf, W2b, b2, ybuf);

  // --- sliced gather (raw sums): ybuf -> hbuf ---
  gather_slice<<<GSB, 256, 0, stream>>>(ybuf, cursor, ell, hbuf);

  // --- head: relu+logmap+classifier ---
  head_mfma<<<NTILE, 256, 0, stream>>>(hbuf, Wc, bc, out);
}